// Round 10
// baseline (191.184 us; speedup 1.0000x reference)
//
#include <hip/hip_runtime.h>

typedef __attribute__((ext_vector_type(8))) short short8;
typedef __attribute__((ext_vector_type(4))) short short4v;
typedef __attribute__((ext_vector_type(4))) float float4v;

#define T_SEQ 2048
#define CDIM 1024
#define NHEAD 16
#define HDIM 64

__device__ __forceinline__ unsigned short f2bf(float f) {
    unsigned u = __builtin_bit_cast(unsigned, f);
    u += 0x7FFF + ((u >> 16) & 1);
    return (unsigned short)(u >> 16);
}

// async global->LDS, 16B per lane. LDS dest wave-uniform base + lane*16B.
__device__ __forceinline__ void gload16(const unsigned short* g,
                                        unsigned short* l) {
    __builtin_amdgcn_global_load_lds(
        (const __attribute__((address_space(1))) unsigned int*)g,
        (__attribute__((address_space(3))) unsigned int*)l, 16, 0, 0);
}

// raw barrier WITHOUT the implicit vmcnt(0) drain of __syncthreads.
__device__ __forceinline__ void phase_barrier() {
    __builtin_amdgcn_sched_barrier(0);
    __builtin_amdgcn_s_barrier();
    __builtin_amdgcn_sched_barrier(0);
}

// ---------------- fused preprocessing: convert + 2 transposes -------------
__global__ __launch_bounds__(256) void preproc(
    const float* __restrict__ x, unsigned short* __restrict__ xb,
    const float* __restrict__ Wa, unsigned short* __restrict__ WaT,
    const float* __restrict__ Wp, unsigned short* __restrict__ WpT) {
    int bid = blockIdx.x, tid = threadIdx.x;
    if (bid < 4096) {
        int i = bid * 256 + tid;
        float4 v = ((const float4*)x)[i];
        ushort4 o;
        o.x = f2bf(v.x); o.y = f2bf(v.y); o.z = f2bf(v.z); o.w = f2bf(v.w);
        ((ushort4*)xb)[i] = o;
        return;
    }
    __shared__ float tile[32][33];
    const float* in;
    unsigned short* out;
    int N, b;
    if (bid < 4096 + 3072) {
        b = bid - 4096; in = Wa; out = WaT; N = 3072;
    } else {
        b = bid - 7168; in = Wp; out = WpT; N = 1024;
    }
    const int K = 1024;
    int kb = (b & 31) * 32, nb = (b >> 5) * 32;
    int tx = tid & 31, ty = tid >> 5;  // ty 0..7
    for (int r = 0; r < 4; r++)
        tile[ty + r * 8][tx] = in[(size_t)(kb + ty + r * 8) * N + nb + tx];
    __syncthreads();
    for (int r = 0; r < 4; r++)
        out[(size_t)(nb + ty + r * 8) * K + kb + tx] = f2bf(tile[tx][ty + r * 8]);
}

// ---------------- QKV GEMM: 128x128, BK=32, 3-buffer counted-vmcnt --------
// R6 proven version (49.2-49.6us), full unroll (R9's unroll-3 was ~equal,
// slightly worse). gload_lds staging, 3-deep rotation, vmcnt(4) never
// drains in main loop. 768 blocks = 3/CU.
__global__ __launch_bounds__(256) void gemm_qkv(
    const unsigned short* __restrict__ A, const unsigned short* __restrict__ Bt,
    unsigned short* __restrict__ dK, unsigned short* __restrict__ dQ,
    unsigned short* __restrict__ dV) {
    const int K = 1024;
    const int NITER = K / 32;  // 32
    __shared__ unsigned short sA[3][128 * 32];
    __shared__ unsigned short sB[3][128 * 32];
    int tid = threadIdx.x, wave = tid >> 6, lane = tid & 63;
    int quad = lane >> 4, l16 = lane & 15;
    int wm = wave >> 1, wn = wave & 1;
    int blockM = blockIdx.y * 128, blockN = blockIdx.x * 128;
    bool swapAB = (blockN >= 2048);  // V part: produce C^T

    const unsigned short* gA = A + (size_t)blockM * K;
    const unsigned short* gB = Bt + (size_t)blockN * K;

    int srow = wave * 32 + (lane >> 2);
    int scol = (lane & 3) * 8;
    const unsigned short* pa0 = gA + (size_t)srow * K + scol;
    const unsigned short* pa1 = pa0 + (size_t)16 * K;
    const unsigned short* pb0 = gB + (size_t)srow * K + scol;
    const unsigned short* pb1 = pb0 + (size_t)16 * K;
    int lo0 = (wave * 32) * 32;
    int lo1 = (wave * 32 + 16) * 32;

    float4v acc[4][4] = {};
    int aoff = (wm * 64 + l16) * 32 + quad * 8;
    int boff = (wn * 64 + l16) * 32 + quad * 8;

    for (int t = 0; t < 2; t++) {
        int kb = t * 32;
        gload16(pa0 + kb, sA[t] + lo0);
        gload16(pa1 + kb, sA[t] + lo1);
        gload16(pb0 + kb, sB[t] + lo0);
        gload16(pb1 + kb, sB[t] + lo1);
    }
    asm volatile("s_waitcnt vmcnt(4)" ::: "memory");
    phase_barrier();

#pragma unroll
    for (int it = 0; it < NITER; it++) {
        int cur = it % 3;
        if (it + 2 < NITER) {
            int kb = (it + 2) * 32;
            int nb = (it + 2) % 3;
            gload16(pa0 + kb, sA[nb] + lo0);
            gload16(pa1 + kb, sA[nb] + lo1);
            gload16(pb0 + kb, sB[nb] + lo0);
            gload16(pb1 + kb, sB[nb] + lo1);
        }
        const unsigned short* cA = sA[cur];
        const unsigned short* cB = sB[cur];
        short8 af[4], bf[4];
        for (int i = 0; i < 4; i++)
            af[i] = *(const short8*)(cA + aoff + i * 16 * 32);
        for (int j = 0; j < 4; j++)
            bf[j] = *(const short8*)(cB + boff + j * 16 * 32);
        if (!swapAB) {
            for (int i = 0; i < 4; i++)
                for (int j = 0; j < 4; j++)
                    acc[i][j] = __builtin_amdgcn_mfma_f32_16x16x32_bf16(
                        af[i], bf[j], acc[i][j], 0, 0, 0);
        } else {
            for (int i = 0; i < 4; i++)
                for (int j = 0; j < 4; j++)
                    acc[i][j] = __builtin_amdgcn_mfma_f32_16x16x32_bf16(
                        bf[j], af[i], acc[i][j], 0, 0, 0);
        }
        if (it + 1 < NITER) {
            if (it + 2 < NITER) {
                asm volatile("s_waitcnt vmcnt(4)" ::: "memory");
            } else {
                asm volatile("s_waitcnt vmcnt(0)" ::: "memory");
            }
            phase_barrier();
        }
    }

    if (!swapAB) {
        const float QSCL = 0.18033688011112042f;  // 0.125 * log2(e)
        for (int i = 0; i < 4; i++)
            for (int j = 0; j < 4; j++)
                for (int r = 0; r < 4; r++) {
                    int m = blockM + wm * 64 + i * 16 + quad * 4 + r;
                    int n = blockN + wn * 64 + j * 16 + l16;
                    int part = n >> 10, c = n & 1023;
                    int h = c >> 6, d = c & 63;
                    int bb = m >> 11, t = m & 2047;
                    int bh = bb * NHEAD + h;
                    if (part == 0) {
                        dK[(((size_t)bh * T_SEQ + t) << 6) + d] = f2bf(acc[i][j][r]);
                    } else {
                        dQ[(((size_t)bh * T_SEQ + t) << 6) + d] =
                            f2bf(acc[i][j][r] * QSCL);
                    }
                }
    } else {
        for (int i = 0; i < 4; i++)
            for (int j = 0; j < 4; j++)
                for (int r = 0; r < 4; r++) {
                    int n = blockN + wn * 64 + j * 16 + quad * 4 + r;
                    int m = blockM + wm * 64 + i * 16 + l16;
                    int c = n & 1023;
                    int h = c >> 6, d = c & 63;
                    int bb = m >> 11, t = m & 2047;
                    int bh = bb * NHEAD + h;
                    dV[((size_t)bh * HDIM + d) * T_SEQ + t] = f2bf(acc[i][j][r]);
                }
    }
}

// ---------------- proj GEMM: 64x128, BK=64, 3-buffer counted-vmcnt --------
// The one proj geometry with 16 MFMA/barrier AND >=2 blocks/CU:
// BM=64 x BN=128, grid (8,64)=512 blocks = 2/CU (R5's 128^2 died at 1/CU).
// Same race-audited qkv pattern, vmcnt re-derived: 6 gloads/tile (A:2,B:4)
// -> vmcnt(6) = tile it+1 landed, it+2 in flight. LDS 3x(64+128)x64x2B
// = 73.7KB -> 2 blocks/CU. 128B-stride ds_read bank aliasing accepted
// (off critical path at 2-phase, T2 regime gate).
__global__ __launch_bounds__(256) void gemm_proj(
    const unsigned short* __restrict__ A, const unsigned short* __restrict__ Bt,
    const float* __restrict__ bias, float* __restrict__ out) {
    const int K = 1024;
    const int NITER = K / 64;  // 16
    __shared__ unsigned short sA[3][64 * 64];
    __shared__ unsigned short sB[3][128 * 64];
    int tid = threadIdx.x, wave = tid >> 6, lane = tid & 63;
    int quad = lane >> 4, l16 = lane & 15;
    int wm = wave >> 1, wn = wave & 1;  // 2M x 2N wave grid
    int blockM = blockIdx.y * 64, blockN = blockIdx.x * 128;

    const unsigned short* gA = A + (size_t)blockM * K;
    const unsigned short* gB = Bt + (size_t)blockN * K;

    // staging: one gload16 covers 8 rows of 64 shorts (128B/row).
    // A: 8 chunks of 8 rows -> 2 per wave. B: 16 chunks -> 4 per wave.
    int lr = lane >> 3;          // 0..7: row within chunk
    int scol = (lane & 7) * 8;   // 0..56 shorts
    const unsigned short* pa0 = gA + (size_t)((wave * 2 + 0) * 8 + lr) * K + scol;
    const unsigned short* pa1 = gA + (size_t)((wave * 2 + 1) * 8 + lr) * K + scol;
    const unsigned short* pb0 = gB + (size_t)((wave * 4 + 0) * 8 + lr) * K + scol;
    const unsigned short* pb1 = gB + (size_t)((wave * 4 + 1) * 8 + lr) * K + scol;
    const unsigned short* pb2 = gB + (size_t)((wave * 4 + 2) * 8 + lr) * K + scol;
    const unsigned short* pb3 = gB + (size_t)((wave * 4 + 3) * 8 + lr) * K + scol;
    int la0 = (wave * 2 + 0) * 8 * 64;
    int la1 = (wave * 2 + 1) * 8 * 64;
    int lb0 = (wave * 4 + 0) * 8 * 64;
    int lb1 = (wave * 4 + 1) * 8 * 64;
    int lb2 = (wave * 4 + 2) * 8 * 64;
    int lb3 = (wave * 4 + 3) * 8 * 64;

    float4v acc[2][4] = {};
    int aoff = (wm * 32 + l16) * 64 + quad * 8;
    int boff = (wn * 64 + l16) * 64 + quad * 8;

    for (int t = 0; t < 2; t++) {
        int kb = t * 64;
        gload16(pa0 + kb, sA[t] + la0);
        gload16(pa1 + kb, sA[t] + la1);
        gload16(pb0 + kb, sB[t] + lb0);
        gload16(pb1 + kb, sB[t] + lb1);
        gload16(pb2 + kb, sB[t] + lb2);
        gload16(pb3 + kb, sB[t] + lb3);
    }
    asm volatile("s_waitcnt vmcnt(6)" ::: "memory");  // tile 0 landed
    phase_barrier();

#pragma unroll
    for (int it = 0; it < NITER; it++) {
        int cur = it % 3;
        if (it + 2 < NITER) {
            int kb = (it + 2) * 64;
            int nb = (it + 2) % 3;
            gload16(pa0 + kb, sA[nb] + la0);
            gload16(pa1 + kb, sA[nb] + la1);
            gload16(pb0 + kb, sB[nb] + lb0);
            gload16(pb1 + kb, sB[nb] + lb1);
            gload16(pb2 + kb, sB[nb] + lb2);
            gload16(pb3 + kb, sB[nb] + lb3);
        }
        const unsigned short* cA = sA[cur];
        const unsigned short* cB = sB[cur];
        short8 af[2][2], bf[4][2];
        for (int i = 0; i < 2; i++)
            for (int ks = 0; ks < 2; ks++)
                af[i][ks] = *(const short8*)(cA + aoff + i * 16 * 64 + ks * 32);
        for (int j = 0; j < 4; j++)
            for (int ks = 0; ks < 2; ks++)
                bf[j][ks] = *(const short8*)(cB + boff + j * 16 * 64 + ks * 32);
        for (int i = 0; i < 2; i++)
            for (int j = 0; j < 4; j++) {
                acc[i][j] = __builtin_amdgcn_mfma_f32_16x16x32_bf16(
                    af[i][0], bf[j][0], acc[i][j], 0, 0, 0);
                acc[i][j] = __builtin_amdgcn_mfma_f32_16x16x32_bf16(
                    af[i][1], bf[j][1], acc[i][j], 0, 0, 0);
            }
        if (it + 1 < NITER) {
            if (it + 2 < NITER) {
                asm volatile("s_waitcnt vmcnt(6)" ::: "memory");
            } else {
                asm volatile("s_waitcnt vmcnt(0)" ::: "memory");
            }
            phase_barrier();
        }
    }

    float bv[4];
    for (int j = 0; j < 4; j++) bv[j] = bias[blockN + wn * 64 + j * 16 + l16];
    for (int i = 0; i < 2; i++)
        for (int j = 0; j < 4; j++)
            for (int r = 0; r < 4; r++) {
                int m = blockM + wm * 32 + i * 16 + quad * 4 + r;
                int n = blockN + wn * 64 + j * 16 + l16;
                out[(size_t)m * CDIM + n] = acc[i][j][r] + bv[j];
            }
}

// ---------------- flash attention v9: cvt_pk packing ----------------------
// R6 proven version (unchanged).
__global__ __launch_bounds__(256) void attn_fwd(
    const unsigned short* __restrict__ Qp, const unsigned short* __restrict__ Kp,
    const unsigned short* __restrict__ Vt, unsigned short* __restrict__ att) {
    __shared__ unsigned short sK[2][64 * 72];
    __shared__ unsigned short sV[2][64 * 72];
    int tid = threadIdx.x, wave = tid >> 6, lane = tid & 63;
    int quad = lane >> 4, l16 = lane & 15;
    int bh = blockIdx.x;
    int bb = bh >> 4, h = bh & 15;
    size_t baseQ = (size_t)bh * T_SEQ * HDIM;  // [t][d]
    size_t baseV = (size_t)bh * HDIM * T_SEQ;  // [d][t]
    int row4 = tid >> 2, seg = tid & 3;

    int xt = 31 - blockIdx.y;
    int qb = xt * 64;
    int qrow = qb + wave * 16 + l16;

    const unsigned short* qr = Qp + baseQ + (size_t)qrow * HDIM;
    short8 qf0 = *(const short8*)(qr + quad * 8);
    short8 qf1 = *(const short8*)(qr + 32 + quad * 8);

    float4v o[4] = {};
    float lsum = 0.f;
    int nt = xt + 1;

    uint4 ka, kb2, va, vb;
    {
        const unsigned short* gk = Kp + baseQ + (size_t)row4 * HDIM + seg * 16;
        const unsigned short* gv = Vt + baseV + (size_t)row4 * T_SEQ + seg * 16;
        ka = *(const uint4*)gk; kb2 = *(const uint4*)(gk + 8);
        va = *(const uint4*)gv; vb = *(const uint4*)(gv + 8);
    }
    *(uint4*)(sK[0] + row4 * 72 + seg * 16) = ka;
    *(uint4*)(sK[0] + row4 * 72 + seg * 16 + 8) = kb2;
    *(uint4*)(sV[0] + row4 * 72 + seg * 16) = va;
    *(uint4*)(sV[0] + row4 * 72 + seg * 16 + 8) = vb;

    const float4v NEG16 = {-16.f, -16.f, -16.f, -16.f};

    for (int t = 0; t < nt; t++) {
        int cur = t & 1;
        __syncthreads();
        if (t + 1 < nt) {
            const unsigned short* gk =
                Kp + baseQ + (size_t)((t + 1) * 64 + row4) * HDIM + seg * 16;
            const unsigned short* gv =
                Vt + baseV + (size_t)row4 * T_SEQ + (t + 1) * 64 + seg * 16;
            ka = *(const uint4*)gk; kb2 = *(const uint4*)(gk + 8);
            va = *(const uint4*)gv; vb = *(const uint4*)(gv + 8);
        }

        const unsigned short* cK = sK[cur];
        const unsigned short* cV = sV[cur];
        float4v s[4];
        __builtin_amdgcn_s_setprio(1);
        for (int sub = 0; sub < 4; sub++) {
            short8 kf0 = *(const short8*)(cK + (sub * 16 + l16) * 72 + quad * 8);
            short8 kf1 =
                *(const short8*)(cK + (sub * 16 + l16) * 72 + 32 + quad * 8);
            float4v z = NEG16;  // fixed-max -16 folded into C-init
            z = __builtin_amdgcn_mfma_f32_16x16x32_bf16(kf0, qf0, z, 0, 0, 0);
            z = __builtin_amdgcn_mfma_f32_16x16x32_bf16(kf1, qf1, z, 0, 0, 0);
            s[sub] = z;
        }
        __builtin_amdgcn_s_setprio(0);

        float e[16];
        bool need_mask = (t * 64 + 63) > (qb + wave * 16);  // wave-uniform
        if (need_mask) {
            int kgb = t * 64 + quad * 4;
            for (int sub = 0; sub < 4; sub++)
                for (int r = 0; r < 4; r++) {
                    float v = __builtin_amdgcn_exp2f(s[sub][r]);
                    v = (kgb + sub * 16 + r <= qrow) ? v : 0.0f;
                    e[sub * 4 + r] = v;
                    lsum += v;
                }
        } else {
            for (int sub = 0; sub < 4; sub++)
                for (int r = 0; r < 4; r++) {
                    float v = __builtin_amdgcn_exp2f(s[sub][r]);
                    e[sub * 4 + r] = v;
                    lsum += v;
                }
        }

        __builtin_amdgcn_s_setprio(1);
        for (int sub = 0; sub < 4; sub++) {
            unsigned lo, hi;
            asm("v_cvt_pk_bf16_f32 %0, %1, %2"
                : "=v"(lo) : "v"(e[sub * 4 + 0]), "v"(e[sub * 4 + 1]));
            asm("v_cvt_pk_bf16_f32 %0, %1, %2"
                : "=v"(hi) : "v"(e[sub * 4 + 2]), "v"(e[sub * 4 + 3]));
            uint2 packed = {lo, hi};
            short4v pf = __builtin_bit_cast(short4v, packed);
            for (int dc = 0; dc < 4; dc++) {
                short4v vf = *(const short4v*)(
                    cV + (dc * 16 + l16) * 72 + sub * 16 + quad * 4);
                o[dc] = __builtin_amdgcn_mfma_f32_16x16x16bf16_1k(
                    vf, pf, o[dc], 0, 0, 0);
            }
        }
        __builtin_amdgcn_s_setprio(0);

        if (t + 1 < nt) {
            int nxt = cur ^ 1;
            *(uint4*)(sK[nxt] + row4 * 72 + seg * 16) = ka;
            *(uint4*)(sK[nxt] + row4 * 72 + seg * 16 + 8) = kb2;
            *(uint4*)(sV[nxt] + row4 * 72 + seg * 16) = va;
            *(uint4*)(sV[nxt] + row4 * 72 + seg * 16 + 8) = vb;
        }
    }

    lsum += __shfl_xor(lsum, 16);
    lsum += __shfl_xor(lsum, 32);
    float inv = 1.0f / lsum;

    __syncthreads();
    for (int dc = 0; dc < 4; dc++) {
        short4v ov;
        for (int r = 0; r < 4; r++) ov[r] = (short)f2bf(o[dc][r] * inv);
        *(short4v*)(sK[0] + wave * 1152 + l16 * 72 + dc * 16 + quad * 4) = ov;
    }
    __syncthreads();
    int orow = lane >> 2, oseg = lane & 3;
    uint4 a = *(const uint4*)(sK[0] + wave * 1152 + orow * 72 + oseg * 16);
    uint4 b = *(const uint4*)(sK[0] + wave * 1152 + orow * 72 + oseg * 16 + 8);
    unsigned short* dst = att +
        (size_t)(bb * T_SEQ + qb + wave * 16 + orow) * CDIM + h * HDIM +
        oseg * 16;
    *(uint4*)dst = a;
    *(uint4*)(dst + 8) = b;
}

// ---------------- launch ----------------
extern "C" void kernel_launch(void* const* d_in, const int* in_sizes, int n_in,
                              void* d_out, int out_size, void* d_ws, size_t ws_size,
                              hipStream_t stream) {
    const float* x      = (const float*)d_in[0];   // [2,2048,1024]
    const float* W_attn = (const float*)d_in[1];   // [1024,3072]
    const float* W_proj = (const float*)d_in[2];   // [1024,1024]
    const float* b_proj = (const float*)d_in[3];   // [1024]
    float* out = (float*)d_out;                    // [2,2048,1024]

    unsigned short* xb   = (unsigned short*)d_ws;          // 4096*1024
    unsigned short* WaT  = xb  + 4096 * 1024;              // 3072*1024 (transposed)
    unsigned short* WpT  = WaT + 3072 * 1024;              // 1024*1024 (transposed)
    unsigned short* Karr = WpT + 1024 * 1024;              // [B,H,T,64]
    unsigned short* Qarr = Karr + 2 * 16 * 2048 * 64;      // [B,H,T,64] pre-scaled
    unsigned short* Varr = Qarr + 2 * 16 * 2048 * 64;      // [B,H,64,T] transposed
    unsigned short* attb = Varr + 2 * 16 * 2048 * 64;      // 4096*1024

    preproc<<<8192, 256, 0, stream>>>(x, xb, W_attn, WaT, W_proj, WpT);
    gemm_qkv<<<dim3(24, 32), 256, 0, stream>>>(xb, WaT, Karr, Qarr, Varr);
    attn_fwd<<<dim3(32, 32), 256, 0, stream>>>(Qarr, Karr, Varr, attb);
    gemm_proj<<<dim3(8, 64), 256, 0, stream>>>(attb, WpT, b_proj, out);
}

// Round 11
// 186.707 us; speedup vs baseline: 1.0240x; 1.0240x over previous
//
#include <hip/hip_runtime.h>

typedef __attribute__((ext_vector_type(8))) short short8;
typedef __attribute__((ext_vector_type(4))) short short4v;
typedef __attribute__((ext_vector_type(4))) float float4v;

#define T_SEQ 2048
#define CDIM 1024
#define NHEAD 16
#define HDIM 64
#define PROW 72  // proj LDS row stride (shorts), BK=64 + pad

__device__ __forceinline__ unsigned short f2bf(float f) {
    unsigned u = __builtin_bit_cast(unsigned, f);
    u += 0x7FFF + ((u >> 16) & 1);
    return (unsigned short)(u >> 16);
}

// async global->LDS, 16B per lane. LDS dest wave-uniform base + lane*16B.
__device__ __forceinline__ void gload16(const unsigned short* g,
                                        unsigned short* l) {
    __builtin_amdgcn_global_load_lds(
        (const __attribute__((address_space(1))) unsigned int*)g,
        (__attribute__((address_space(3))) unsigned int*)l, 16, 0, 0);
}

// raw barrier WITHOUT the implicit vmcnt(0) drain of __syncthreads.
__device__ __forceinline__ void phase_barrier() {
    __builtin_amdgcn_sched_barrier(0);
    __builtin_amdgcn_s_barrier();
    __builtin_amdgcn_sched_barrier(0);
}

// ---------------- fused preprocessing: convert + 2 transposes -------------
__global__ __launch_bounds__(256) void preproc(
    const float* __restrict__ x, unsigned short* __restrict__ xb,
    const float* __restrict__ Wa, unsigned short* __restrict__ WaT,
    const float* __restrict__ Wp, unsigned short* __restrict__ WpT) {
    int bid = blockIdx.x, tid = threadIdx.x;
    if (bid < 4096) {
        int i = bid * 256 + tid;
        float4 v = ((const float4*)x)[i];
        ushort4 o;
        o.x = f2bf(v.x); o.y = f2bf(v.y); o.z = f2bf(v.z); o.w = f2bf(v.w);
        ((ushort4*)xb)[i] = o;
        return;
    }
    __shared__ float tile[32][33];
    const float* in;
    unsigned short* out;
    int N, b;
    if (bid < 4096 + 3072) {
        b = bid - 4096; in = Wa; out = WaT; N = 3072;
    } else {
        b = bid - 7168; in = Wp; out = WpT; N = 1024;
    }
    const int K = 1024;
    int kb = (b & 31) * 32, nb = (b >> 5) * 32;
    int tx = tid & 31, ty = tid >> 5;  // ty 0..7
    for (int r = 0; r < 4; r++)
        tile[ty + r * 8][tx] = in[(size_t)(kb + ty + r * 8) * N + nb + tx];
    __syncthreads();
    for (int r = 0; r < 4; r++)
        out[(size_t)(nb + ty + r * 8) * K + kb + tx] = f2bf(tile[tx][ty + r * 8]);
}

// ---------------- QKV GEMM: 128x128, BK=32, 3-buffer counted-vmcnt --------
// R6 proven structure (49.2-49.6us). R11 adds T1 XCD swizzle: 768 blocks,
// 768%8==0 -> bijective wgid=(lin%8)*96+lin/8; each XCD gets a contiguous
// 96-block chunk (4 M-strips x all N) -> per-XCD read working set 9->7MB
// vs 4MB L2. Pure index permutation, zero correctness risk.
__global__ __launch_bounds__(256) void gemm_qkv(
    const unsigned short* __restrict__ A, const unsigned short* __restrict__ Bt,
    unsigned short* __restrict__ dK, unsigned short* __restrict__ dQ,
    unsigned short* __restrict__ dV) {
    const int K = 1024;
    const int NITER = K / 32;  // 32
    __shared__ unsigned short sA[3][128 * 32];
    __shared__ unsigned short sB[3][128 * 32];
    int tid = threadIdx.x, wave = tid >> 6, lane = tid & 63;
    int quad = lane >> 4, l16 = lane & 15;
    int wm = wave >> 1, wn = wave & 1;

    // T1 XCD swizzle (bijective: 768 % 8 == 0, 96 blocks/XCD)
    int lin = blockIdx.y * 24 + blockIdx.x;
    int swz = (lin & 7) * 96 + (lin >> 3);
    int bx = swz % 24, by = swz / 24;
    int blockM = by * 128, blockN = bx * 128;
    bool swapAB = (blockN >= 2048);  // V part: produce C^T

    const unsigned short* gA = A + (size_t)blockM * K;
    const unsigned short* gB = Bt + (size_t)blockN * K;

    int srow = wave * 32 + (lane >> 2);
    int scol = (lane & 3) * 8;
    const unsigned short* pa0 = gA + (size_t)srow * K + scol;
    const unsigned short* pa1 = pa0 + (size_t)16 * K;
    const unsigned short* pb0 = gB + (size_t)srow * K + scol;
    const unsigned short* pb1 = pb0 + (size_t)16 * K;
    int lo0 = (wave * 32) * 32;
    int lo1 = (wave * 32 + 16) * 32;

    float4v acc[4][4] = {};
    int aoff = (wm * 64 + l16) * 32 + quad * 8;
    int boff = (wn * 64 + l16) * 32 + quad * 8;

    for (int t = 0; t < 2; t++) {
        int kb = t * 32;
        gload16(pa0 + kb, sA[t] + lo0);
        gload16(pa1 + kb, sA[t] + lo1);
        gload16(pb0 + kb, sB[t] + lo0);
        gload16(pb1 + kb, sB[t] + lo1);
    }
    asm volatile("s_waitcnt vmcnt(4)" ::: "memory");
    phase_barrier();

#pragma unroll
    for (int it = 0; it < NITER; it++) {
        int cur = it % 3;
        if (it + 2 < NITER) {
            int kb = (it + 2) * 32;
            int nb = (it + 2) % 3;
            gload16(pa0 + kb, sA[nb] + lo0);
            gload16(pa1 + kb, sA[nb] + lo1);
            gload16(pb0 + kb, sB[nb] + lo0);
            gload16(pb1 + kb, sB[nb] + lo1);
        }
        const unsigned short* cA = sA[cur];
        const unsigned short* cB = sB[cur];
        short8 af[4], bf[4];
        for (int i = 0; i < 4; i++)
            af[i] = *(const short8*)(cA + aoff + i * 16 * 32);
        for (int j = 0; j < 4; j++)
            bf[j] = *(const short8*)(cB + boff + j * 16 * 32);
        if (!swapAB) {
            for (int i = 0; i < 4; i++)
                for (int j = 0; j < 4; j++)
                    acc[i][j] = __builtin_amdgcn_mfma_f32_16x16x32_bf16(
                        af[i], bf[j], acc[i][j], 0, 0, 0);
        } else {
            for (int i = 0; i < 4; i++)
                for (int j = 0; j < 4; j++)
                    acc[i][j] = __builtin_amdgcn_mfma_f32_16x16x32_bf16(
                        bf[j], af[i], acc[i][j], 0, 0, 0);
        }
        if (it + 1 < NITER) {
            if (it + 2 < NITER) {
                asm volatile("s_waitcnt vmcnt(4)" ::: "memory");
            } else {
                asm volatile("s_waitcnt vmcnt(0)" ::: "memory");
            }
            phase_barrier();
        }
    }

    if (!swapAB) {
        const float QSCL = 0.18033688011112042f;  // 0.125 * log2(e)
        for (int i = 0; i < 4; i++)
            for (int j = 0; j < 4; j++)
                for (int r = 0; r < 4; r++) {
                    int m = blockM + wm * 64 + i * 16 + quad * 4 + r;
                    int n = blockN + wn * 64 + j * 16 + l16;
                    int part = n >> 10, c = n & 1023;
                    int h = c >> 6, d = c & 63;
                    int bb = m >> 11, t = m & 2047;
                    int bh = bb * NHEAD + h;
                    if (part == 0) {
                        dK[(((size_t)bh * T_SEQ + t) << 6) + d] = f2bf(acc[i][j][r]);
                    } else {
                        dQ[(((size_t)bh * T_SEQ + t) << 6) + d] =
                            f2bf(acc[i][j][r] * QSCL);
                    }
                }
    } else {
        for (int i = 0; i < 4; i++)
            for (int j = 0; j < 4; j++)
                for (int r = 0; r < 4; r++) {
                    int n = blockN + wn * 64 + j * 16 + quad * 4 + r;
                    int m = blockM + wm * 64 + i * 16 + l16;
                    int c = n & 1023;
                    int h = c >> 6, d = c & 63;
                    int bb = m >> 11, t = m & 2047;
                    int bh = bb * NHEAD + h;
                    dV[((size_t)bh * HDIM + d) * T_SEQ + t] = f2bf(acc[i][j][r]);
                }
    }
}

// ---------------- proj GEMM: 64x64 tile, BK=64, reg-prefetch --------------
// R0 proven version, FINAL. 1024 blocks = 4/CU. Beat 128^2 T4 (1/CU, +11us,
// R5) and 64x128 T4 (2/CU, +4.5us, R10): cross-block overlap at 4/CU wins
// over deeper pipelines at K=1024.
__global__ __launch_bounds__(256) void gemm_proj(
    const unsigned short* __restrict__ A, const unsigned short* __restrict__ Bt,
    const float* __restrict__ bias, float* __restrict__ out) {
    const int K = 1024;
    const int NITER = K / 64;
    __shared__ unsigned short sA[2][64 * PROW];
    __shared__ unsigned short sB[2][64 * PROW];
    int tid = threadIdx.x, wave = tid >> 6, lane = tid & 63;
    int quad = lane >> 4, l16 = lane & 15;
    int wm = wave >> 1, wn = wave & 1;
    int blockM = blockIdx.y * 64, blockN = blockIdx.x * 64;

    int srow = tid >> 3;      // 0..31
    int sseg = tid & 7;       // 0..7
    const unsigned short* gA0 = A + (size_t)(blockM + srow) * K + sseg * 8;
    const unsigned short* gA1 = gA0 + (size_t)32 * K;
    const unsigned short* gB0 = Bt + (size_t)(blockN + srow) * K + sseg * 8;
    const unsigned short* gB1 = gB0 + (size_t)32 * K;
    int so0 = srow * PROW + sseg * 8;
    int so1 = (srow + 32) * PROW + sseg * 8;

    float4v acc[2][2] = {};
    uint4 ra0, ra1, rb0, rb1;

    ra0 = *(const uint4*)gA0; ra1 = *(const uint4*)gA1;
    rb0 = *(const uint4*)gB0; rb1 = *(const uint4*)gB1;
    *(uint4*)(sA[0] + so0) = ra0;
    *(uint4*)(sA[0] + so1) = ra1;
    *(uint4*)(sB[0] + so0) = rb0;
    *(uint4*)(sB[0] + so1) = rb1;

    int aoff = (wm * 32 + l16) * PROW + quad * 8;
    int boff = (wn * 32 + l16) * PROW + quad * 8;

    for (int it = 0; it < NITER; it++) {
        int cur = it & 1;
        __syncthreads();
        if (it + 1 < NITER) {
            int kb = (it + 1) * 64;
            ra0 = *(const uint4*)(gA0 + kb); ra1 = *(const uint4*)(gA1 + kb);
            rb0 = *(const uint4*)(gB0 + kb); rb1 = *(const uint4*)(gB1 + kb);
        }
        const unsigned short* cA = sA[cur];
        const unsigned short* cB = sB[cur];
        short8 af[2][2], bf[2][2];
        for (int i = 0; i < 2; i++)
            for (int k = 0; k < 2; k++)
                af[i][k] = *(const short8*)(cA + aoff + i * 16 * PROW + k * 32);
        for (int j = 0; j < 2; j++)
            for (int k = 0; k < 2; k++)
                bf[j][k] = *(const short8*)(cB + boff + j * 16 * PROW + k * 32);
        for (int i = 0; i < 2; i++)
            for (int j = 0; j < 2; j++) {
                acc[i][j] = __builtin_amdgcn_mfma_f32_16x16x32_bf16(
                    af[i][0], bf[j][0], acc[i][j], 0, 0, 0);
                acc[i][j] = __builtin_amdgcn_mfma_f32_16x16x32_bf16(
                    af[i][1], bf[j][1], acc[i][j], 0, 0, 0);
            }
        if (it + 1 < NITER) {
            int nxt = cur ^ 1;
            *(uint4*)(sA[nxt] + so0) = ra0;
            *(uint4*)(sA[nxt] + so1) = ra1;
            *(uint4*)(sB[nxt] + so0) = rb0;
            *(uint4*)(sB[nxt] + so1) = rb1;
        }
    }

    for (int i = 0; i < 2; i++)
        for (int j = 0; j < 2; j++)
            for (int r = 0; r < 4; r++) {
                int m = blockM + wm * 32 + i * 16 + quad * 4 + r;
                int n = blockN + wn * 32 + j * 16 + l16;
                out[(size_t)m * CDIM + n] = acc[i][j][r] + bias[n];
            }
}

// ---------------- flash attention v9: cvt_pk packing ----------------------
// R6 proven version (unchanged).
__global__ __launch_bounds__(256) void attn_fwd(
    const unsigned short* __restrict__ Qp, const unsigned short* __restrict__ Kp,
    const unsigned short* __restrict__ Vt, unsigned short* __restrict__ att) {
    __shared__ unsigned short sK[2][64 * 72];
    __shared__ unsigned short sV[2][64 * 72];
    int tid = threadIdx.x, wave = tid >> 6, lane = tid & 63;
    int quad = lane >> 4, l16 = lane & 15;
    int bh = blockIdx.x;
    int bb = bh >> 4, h = bh & 15;
    size_t baseQ = (size_t)bh * T_SEQ * HDIM;  // [t][d]
    size_t baseV = (size_t)bh * HDIM * T_SEQ;  // [d][t]
    int row4 = tid >> 2, seg = tid & 3;

    int xt = 31 - blockIdx.y;
    int qb = xt * 64;
    int qrow = qb + wave * 16 + l16;

    const unsigned short* qr = Qp + baseQ + (size_t)qrow * HDIM;
    short8 qf0 = *(const short8*)(qr + quad * 8);
    short8 qf1 = *(const short8*)(qr + 32 + quad * 8);

    float4v o[4] = {};
    float lsum = 0.f;
    int nt = xt + 1;

    uint4 ka, kb2, va, vb;
    {
        const unsigned short* gk = Kp + baseQ + (size_t)row4 * HDIM + seg * 16;
        const unsigned short* gv = Vt + baseV + (size_t)row4 * T_SEQ + seg * 16;
        ka = *(const uint4*)gk; kb2 = *(const uint4*)(gk + 8);
        va = *(const uint4*)gv; vb = *(const uint4*)(gv + 8);
    }
    *(uint4*)(sK[0] + row4 * 72 + seg * 16) = ka;
    *(uint4*)(sK[0] + row4 * 72 + seg * 16 + 8) = kb2;
    *(uint4*)(sV[0] + row4 * 72 + seg * 16) = va;
    *(uint4*)(sV[0] + row4 * 72 + seg * 16 + 8) = vb;

    const float4v NEG16 = {-16.f, -16.f, -16.f, -16.f};

    for (int t = 0; t < nt; t++) {
        int cur = t & 1;
        __syncthreads();
        if (t + 1 < nt) {
            const unsigned short* gk =
                Kp + baseQ + (size_t)((t + 1) * 64 + row4) * HDIM + seg * 16;
            const unsigned short* gv =
                Vt + baseV + (size_t)row4 * T_SEQ + (t + 1) * 64 + seg * 16;
            ka = *(const uint4*)gk; kb2 = *(const uint4*)(gk + 8);
            va = *(const uint4*)gv; vb = *(const uint4*)(gv + 8);
        }

        const unsigned short* cK = sK[cur];
        const unsigned short* cV = sV[cur];
        float4v s[4];
        __builtin_amdgcn_s_setprio(1);
        for (int sub = 0; sub < 4; sub++) {
            short8 kf0 = *(const short8*)(cK + (sub * 16 + l16) * 72 + quad * 8);
            short8 kf1 =
                *(const short8*)(cK + (sub * 16 + l16) * 72 + 32 + quad * 8);
            float4v z = NEG16;  // fixed-max -16 folded into C-init
            z = __builtin_amdgcn_mfma_f32_16x16x32_bf16(kf0, qf0, z, 0, 0, 0);
            z = __builtin_amdgcn_mfma_f32_16x16x32_bf16(kf1, qf1, z, 0, 0, 0);
            s[sub] = z;
        }
        __builtin_amdgcn_s_setprio(0);

        float e[16];
        bool need_mask = (t * 64 + 63) > (qb + wave * 16);  // wave-uniform
        if (need_mask) {
            int kgb = t * 64 + quad * 4;
            for (int sub = 0; sub < 4; sub++)
                for (int r = 0; r < 4; r++) {
                    float v = __builtin_amdgcn_exp2f(s[sub][r]);
                    v = (kgb + sub * 16 + r <= qrow) ? v : 0.0f;
                    e[sub * 4 + r] = v;
                    lsum += v;
                }
        } else {
            for (int sub = 0; sub < 4; sub++)
                for (int r = 0; r < 4; r++) {
                    float v = __builtin_amdgcn_exp2f(s[sub][r]);
                    e[sub * 4 + r] = v;
                    lsum += v;
                }
        }

        __builtin_amdgcn_s_setprio(1);
        for (int sub = 0; sub < 4; sub++) {
            unsigned lo, hi;
            asm("v_cvt_pk_bf16_f32 %0, %1, %2"
                : "=v"(lo) : "v"(e[sub * 4 + 0]), "v"(e[sub * 4 + 1]));
            asm("v_cvt_pk_bf16_f32 %0, %1, %2"
                : "=v"(hi) : "v"(e[sub * 4 + 2]), "v"(e[sub * 4 + 3]));
            uint2 packed = {lo, hi};
            short4v pf = __builtin_bit_cast(short4v, packed);
            for (int dc = 0; dc < 4; dc++) {
                short4v vf = *(const short4v*)(
                    cV + (dc * 16 + l16) * 72 + sub * 16 + quad * 4);
                o[dc] = __builtin_amdgcn_mfma_f32_16x16x16bf16_1k(
                    vf, pf, o[dc], 0, 0, 0);
            }
        }
        __builtin_amdgcn_s_setprio(0);

        if (t + 1 < nt) {
            int nxt = cur ^ 1;
            *(uint4*)(sK[nxt] + row4 * 72 + seg * 16) = ka;
            *(uint4*)(sK[nxt] + row4 * 72 + seg * 16 + 8) = kb2;
            *(uint4*)(sV[nxt] + row4 * 72 + seg * 16) = va;
            *(uint4*)(sV[nxt] + row4 * 72 + seg * 16 + 8) = vb;
        }
    }

    lsum += __shfl_xor(lsum, 16);
    lsum += __shfl_xor(lsum, 32);
    float inv = 1.0f / lsum;

    __syncthreads();
    for (int dc = 0; dc < 4; dc++) {
        short4v ov;
        for (int r = 0; r < 4; r++) ov[r] = (short)f2bf(o[dc][r] * inv);
        *(short4v*)(sK[0] + wave * 1152 + l16 * 72 + dc * 16 + quad * 4) = ov;
    }
    __syncthreads();
    int orow = lane >> 2, oseg = lane & 3;
    uint4 a = *(const uint4*)(sK[0] + wave * 1152 + orow * 72 + oseg * 16);
    uint4 b = *(const uint4*)(sK[0] + wave * 1152 + orow * 72 + oseg * 16 + 8);
    unsigned short* dst = att +
        (size_t)(bb * T_SEQ + qb + wave * 16 + orow) * CDIM + h * HDIM +
        oseg * 16;
    *(uint4*)dst = a;
    *(uint4*)(dst + 8) = b;
}

// ---------------- launch ----------------
extern "C" void kernel_launch(void* const* d_in, const int* in_sizes, int n_in,
                              void* d_out, int out_size, void* d_ws, size_t ws_size,
                              hipStream_t stream) {
    const float* x      = (const float*)d_in[0];   // [2,2048,1024]
    const float* W_attn = (const float*)d_in[1];   // [1024,3072]
    const float* W_proj = (const float*)d_in[2];   // [1024,1024]
    const float* b_proj = (const float*)d_in[3];   // [1024]
    float* out = (float*)d_out;                    // [2,2048,1024]

    unsigned short* xb   = (unsigned short*)d_ws;          // 4096*1024
    unsigned short* WaT  = xb  + 4096 * 1024;              // 3072*1024 (transposed)
    unsigned short* WpT  = WaT + 3072 * 1024;              // 1024*1024 (transposed)
    unsigned short* Karr = WpT + 1024 * 1024;              // [B,H,T,64]
    unsigned short* Qarr = Karr + 2 * 16 * 2048 * 64;      // [B,H,T,64] pre-scaled
    unsigned short* Varr = Qarr + 2 * 16 * 2048 * 64;      // [B,H,64,T] transposed
    unsigned short* attb = Varr + 2 * 16 * 2048 * 64;      // 4096*1024

    preproc<<<8192, 256, 0, stream>>>(x, xb, W_attn, WaT, W_proj, WpT);
    gemm_qkv<<<dim3(24, 32), 256, 0, stream>>>(xb, WaT, Karr, Qarr, Varr);
    attn_fwd<<<dim3(32, 32), 256, 0, stream>>>(Qarr, Karr, Varr, attb);
    gemm_proj<<<dim3(16, 64), 256, 0, stream>>>(attb, WpT, b_proj, out);
}